// Round 1
// baseline (193.336 us; speedup 1.0000x reference)
//
#include <hip/hip_runtime.h>
#include <cstddef>

namespace {
constexpr int B_  = 128;
constexpr int H_  = 256;
constexpr int W2_ = 256;
constexpr int HW  = H_ * W2_;     // 65536
constexpr int EMB_ = 64;
constexpr int NF  = EMB_ + 18;    // 82
constexpr int KCHUNKS = 512;
constexpr int KC = HW / KCHUNKS;  // 128 k per chunk
constexpr int KB = 64;            // k-step staged in LDS
}

// ---------------- Encoder: split-K partial GEMM ----------------
// feats_partial[c][m][n] = sum_{k in chunk c} x[m][k] * W_enc[k][n]
// Block covers all 128 m x all 82 n for one k-chunk.
// wave0: m 0-63  n 0-40 | wave1: m 64-127 n 0-40
// wave2: m 0-63  n 41-81| wave3: m 64-127 n 41-81
__global__ __launch_bounds__(256) void enc_partial_k(
    const float* __restrict__ x, const float* __restrict__ Wenc,
    float* __restrict__ partial)
{
    __shared__ float xs[128][KB + 1];
    const int tid  = threadIdx.x;
    const int lane = tid & 63;
    const int wave = tid >> 6;
    const int k0   = blockIdx.x * KC;
    const int m    = ((wave & 1) << 6) + lane;
    const int n0   = __builtin_amdgcn_readfirstlane((wave >> 1) * 41);

    float acc[41];
#pragma unroll
    for (int j = 0; j < 41; ++j) acc[j] = 0.f;

    const int fper    = KB / 4;        // 16 float4 per row
    const int rowstep = 256 / fper;    // 16 rows per sweep
    const int fr = tid & (fper - 1);
    const int r0 = tid / fper;

    for (int ks = 0; ks < KC; ks += KB) {
        __syncthreads();
#pragma unroll
        for (int rr = 0; rr < 128; rr += rowstep) {
            const int r = r0 + rr;
            const float4 v = *reinterpret_cast<const float4*>(
                &x[(size_t)r * HW + (size_t)(k0 + ks) + fr * 4]);
            xs[r][fr * 4 + 0] = v.x;
            xs[r][fr * 4 + 1] = v.y;
            xs[r][fr * 4 + 2] = v.z;
            xs[r][fr * 4 + 3] = v.w;
        }
        __syncthreads();
#pragma unroll 4
        for (int kk = 0; kk < KB; ++kk) {
            const float xv = xs[m][kk];
            const float* __restrict__ wr =
                Wenc + (size_t)(k0 + ks + kk) * NF + n0;
#pragma unroll
            for (int j = 0; j < 41; ++j) acc[j] = fmaf(xv, wr[j], acc[j]);
        }
    }
    float* __restrict__ pout =
        partial + (size_t)blockIdx.x * (B_ * NF) + (size_t)m * NF + n0;
#pragma unroll
    for (int j = 0; j < 41; ++j) pout[j] = acc[j];
}

// ---------------- Encoder: reduce partials + bias ----------------
__global__ void enc_reduce_k(const float* __restrict__ partial,
                             const float* __restrict__ benc,
                             float* __restrict__ feats)
{
    const int i = blockIdx.x * blockDim.x + threadIdx.x;
    if (i >= B_ * NF) return;
    float s = benc[i % NF];
    for (int c = 0; c < KCHUNKS; ++c)
        s += partial[(size_t)c * (B_ * NF) + i];
    feats[i] = s;
}

// ---------------- Decoder GEMM: pred = emb @ W_dec + b_dec ----------------
// One block: all 128 m x 256-wide p-tile. W_dec read exactly once.
__global__ __launch_bounds__(256) void decoder_k(
    const float* __restrict__ feats, const float* __restrict__ Wdec,
    const float* __restrict__ bdec, float* __restrict__ pred)
{
    __shared__ float embT[EMB_][B_];   // [k][m], 32 KB
    const int tid = threadIdx.x;
    for (int i = tid; i < EMB_ * B_; i += 256) {
        const int k  = i >> 7;     // 0..63
        const int mm = i & 127;
        embT[k][mm] = feats[(size_t)mm * NF + k];
    }
    __syncthreads();

    const int tp = tid & 63;
    const int tm = tid >> 6;                  // wave-uniform
    const int p0 = blockIdx.x * 256 + tp * 4;
    const int mb = tm * 32;

    float acc[32][4];
#pragma unroll
    for (int mm = 0; mm < 32; ++mm)
#pragma unroll
        for (int q = 0; q < 4; ++q) acc[mm][q] = 0.f;

#pragma unroll 2
    for (int k = 0; k < EMB_; ++k) {
        const float4 w = *reinterpret_cast<const float4*>(&Wdec[(size_t)k * HW + p0]);
        const float* e = &embT[k][mb];        // wave-uniform LDS broadcast
#pragma unroll
        for (int mm = 0; mm < 32; ++mm) {
            const float ev = e[mm];
            acc[mm][0] = fmaf(ev, w.x, acc[mm][0]);
            acc[mm][1] = fmaf(ev, w.y, acc[mm][1]);
            acc[mm][2] = fmaf(ev, w.z, acc[mm][2]);
            acc[mm][3] = fmaf(ev, w.w, acc[mm][3]);
        }
    }
    const float4 bd = *reinterpret_cast<const float4*>(&bdec[p0]);
#pragma unroll
    for (int mm = 0; mm < 32; ++mm) {
        float4 o;
        o.x = acc[mm][0] + bd.x;
        o.y = acc[mm][1] + bd.y;
        o.z = acc[mm][2] + bd.z;
        o.w = acc[mm][3] + bd.w;
        *reinterpret_cast<float4*>(&pred[(size_t)(mb + mm) * HW + p0]) = o;
    }
}

// ---------------- Bilinear affine grid-sample (zero padding) ----------------
// theta_sel: 0 = scaler_shear (cols 64..69), 1 = rotation (70..75), 2 = translation (76..81)
__global__ __launch_bounds__(256) void gsample_k(
    const float* __restrict__ src, float* __restrict__ dst,
    const float* __restrict__ feats, int theta_sel)
{
    const int b  = blockIdx.x >> 8;
    const int y  = blockIdx.x & 255;
    const int xq = threadIdx.x;

    const float* th = feats + (size_t)b * NF + EMB_ + theta_sel * 6;
    const float t00 = th[0], t01 = th[1], t02 = th[2];
    const float t10 = th[3], t11 = th[4], t12 = th[5];

    // xs = (2i+1)/W - 1  (exact in f32: power-of-two division)
    const float X = (float)(2 * xq + 1) * (1.f / 256.f) - 1.f;
    const float Y = (float)(2 * y  + 1) * (1.f / 256.f) - 1.f;

    const float gx = t00 * X + t01 * Y + t02;
    const float gy = t10 * X + t11 * Y + t12;

    const float ix = (gx + 1.f) * 128.f - 0.5f;
    const float iy = (gy + 1.f) * 128.f - 0.5f;
    const float ix0 = floorf(ix);
    const float iy0 = floorf(iy);
    const float wx1 = ix - ix0, wx0 = 1.f - wx1;
    const float wy1 = iy - iy0, wy0 = 1.f - wy1;

    const float* sb = src + ((size_t)b << 16);
    auto tap = [&](float xf, float yf) -> float {
        const bool valid = (xf >= 0.f) && (xf < 256.f) &&
                           (yf >= 0.f) && (yf < 256.f);
        const int xi = (int)fminf(fmaxf(xf, 0.f), 255.f);
        const int yi = (int)fminf(fmaxf(yf, 0.f), 255.f);
        const float v = sb[(yi << 8) + xi];
        return valid ? v : 0.f;
    };
    const float v00 = tap(ix0,       iy0);
    const float v10 = tap(ix0 + 1.f, iy0);
    const float v01 = tap(ix0,       iy0 + 1.f);
    const float v11 = tap(ix0 + 1.f, iy0 + 1.f);

    dst[((size_t)blockIdx.x << 8) + xq] =
        v00 * (wx0 * wy0) + v10 * (wx1 * wy0) +
        v01 * (wx0 * wy1) + v11 * (wx1 * wy1);
}

extern "C" void kernel_launch(void* const* d_in, const int* in_sizes, int n_in,
                              void* d_out, int out_size, void* d_ws, size_t ws_size,
                              hipStream_t stream)
{
    const float* x    = (const float*)d_in[0];
    const float* Wenc = (const float*)d_in[1];
    const float* benc = (const float*)d_in[2];
    const float* Wdec = (const float*)d_in[3];
    const float* bdec = (const float*)d_in[4];
    float* out = (float*)d_out;

    float* ws      = (float*)d_ws;
    float* partial = ws;                        // 512*10496 floats (consumed before imgA written)
    float* imgA    = ws;                        // 8.4M floats, overlaps partial region
    float* feats   = ws + (size_t)B_ * HW;      // 10496 floats

    enc_partial_k<<<KCHUNKS, 256, 0, stream>>>(x, Wenc, partial);
    enc_reduce_k<<<(B_ * NF + 255) / 256, 256, 0, stream>>>(partial, benc, feats);
    decoder_k<<<HW / 256, 256, 0, stream>>>(feats, Wdec, bdec, imgA);
    // reference order: grid_3 (translation), grid_1 (scaler_shear), grid_2 (rotation)
    gsample_k<<<B_ * H_, 256, 0, stream>>>(imgA, out, feats, 2);
    gsample_k<<<B_ * H_, 256, 0, stream>>>(out, imgA, feats, 0);
    gsample_k<<<B_ * H_, 256, 0, stream>>>(imgA, out, feats, 1);
}

// Round 2
// 156.832 us; speedup vs baseline: 1.2328x; 1.2328x over previous
//
#include <hip/hip_runtime.h>
#include <cstddef>

namespace {
constexpr int B_   = 128;
constexpr int H_   = 256;
constexpr int W2_  = 256;
constexpr int HW   = H_ * W2_;     // 65536
constexpr int EMB_ = 64;
constexpr int NF   = EMB_ + 18;    // 82
constexpr int BNF  = B_ * NF;      // 10496
constexpr int KCH  = 512;          // k-chunks (grid of stage 1)
constexpr int KC   = HW / KCH;     // 128 k per block
constexpr int KB   = 32;           // k per LDS stage
constexpr int CB2  = 16;           // c-blocks in reduce level 1
}

// ---------------- Encoder stage 1: split-K, LDS-tiled both operands ----------
// Block (512 thr) computes full 128m x 82n partial for its 128-k chunk.
// Thread tile: 4m x 6n. xs is [k][m] (transposed) for contiguous-m b128 reads.
__global__ __launch_bounds__(512) void enc_partial_k(
    const float* __restrict__ x, const float* __restrict__ Wenc,
    float* __restrict__ partial)
{
    __shared__ __align__(16) float xs[KB][132];        // [k][m], pad 4
    __shared__ __align__(16) float wsf[KB * NF + 16];  // flat [k*82+n]

    const int tid = threadIdx.x;
    const int k0  = blockIdx.x * KC;
    const int tm  = tid >> 4;       // 0..31
    const int tn  = tid & 15;       // 0..15
    const int m0  = tm * 4;
    const int n0  = tn * 6;         // 0,6,...,90 (>=82 threads compute garbage, never store)

    float acc[4][6];
#pragma unroll
    for (int i = 0; i < 4; ++i)
#pragma unroll
        for (int j = 0; j < 6; ++j) acc[i][j] = 0.f;

    for (int ks = 0; ks < KC; ks += KB) {
        __syncthreads();
        // stage x[*, k0+ks .. +31] transposed into xs[k][m]
        {
            const int m  = tid >> 2;       // 0..127
            const int fp = tid & 3;
#pragma unroll
            for (int s = 0; s < 2; ++s) {
                const int f = fp + 4 * s;  // 0..7: 64B-contiguous per row per instr
                const float4 v = *reinterpret_cast<const float4*>(
                    &x[(size_t)m * HW + (size_t)(k0 + ks) + f * 4]);
                xs[f * 4 + 0][m] = v.x;
                xs[f * 4 + 1][m] = v.y;
                xs[f * 4 + 2][m] = v.z;
                xs[f * 4 + 3][m] = v.w;
            }
        }
        // stage Wenc rows k0+ks .. +31 (flat contiguous: KB*82 = 2624 floats)
        {
            const float4* src = reinterpret_cast<const float4*>(
                Wenc + (size_t)(k0 + ks) * NF);
            float4* dst = reinterpret_cast<float4*>(wsf);
            for (int i4 = tid; i4 < (KB * NF) / 4; i4 += 512)
                dst[i4] = src[i4];
        }
        __syncthreads();

#pragma unroll 4
        for (int kk = 0; kk < KB; ++kk) {
            const float4 ev = *reinterpret_cast<const float4*>(&xs[kk][m0]);
            const float* wr = &wsf[kk * NF + n0];
            float w[6];
#pragma unroll
            for (int j = 0; j < 6; ++j) w[j] = wr[j];
#pragma unroll
            for (int j = 0; j < 6; ++j) {
                acc[0][j] = fmaf(ev.x, w[j], acc[0][j]);
                acc[1][j] = fmaf(ev.y, w[j], acc[1][j]);
                acc[2][j] = fmaf(ev.z, w[j], acc[2][j]);
                acc[3][j] = fmaf(ev.w, w[j], acc[3][j]);
            }
        }
    }

    if (n0 < NF) {
        float* pout = partial + (size_t)blockIdx.x * BNF;
#pragma unroll
        for (int i = 0; i < 4; ++i)
#pragma unroll
            for (int j = 0; j < 6; ++j)
                if (n0 + j < NF) pout[(m0 + i) * NF + n0 + j] = acc[i][j];
    }
}

// ---------------- Encoder reduce, level 1: 512 -> 16 ----------------
__global__ __launch_bounds__(256) void enc_reduce1(
    const float* __restrict__ partial, float* __restrict__ partial2)
{
    const int i = blockIdx.x * 256 + threadIdx.x;
    if (i >= BNF) return;
    const float* p = partial + (size_t)blockIdx.y * (KCH / CB2) * BNF + i;
    float s = 0.f;
#pragma unroll 8
    for (int c = 0; c < KCH / CB2; ++c) s += p[(size_t)c * BNF];
    partial2[(size_t)blockIdx.y * BNF + i] = s;
}

// ---------------- Encoder reduce, level 2: 16 -> 1 (+bias) ----------------
__global__ __launch_bounds__(256) void enc_reduce2(
    const float* __restrict__ partial2, const float* __restrict__ benc,
    float* __restrict__ feats)
{
    const int i = blockIdx.x * 256 + threadIdx.x;
    if (i >= BNF) return;
    float s = benc[i % NF];
#pragma unroll
    for (int j = 0; j < CB2; ++j) s += partial2[(size_t)j * BNF + i];
    feats[i] = s;
}

// ---------------- Decoder GEMM: pred = emb @ W_dec + b_dec ----------------
// 1024 blocks, each: all 128 m x 64-col tile. Thread tile 8m x 4p.
__global__ __launch_bounds__(256) void decoder_k(
    const float* __restrict__ feats, const float* __restrict__ Wdec,
    const float* __restrict__ bdec, float* __restrict__ pred)
{
    __shared__ __align__(16) float embT[EMB_][B_];   // [k][m], 32 KB
    const int tid = threadIdx.x;
    for (int i = tid; i < EMB_ * B_; i += 256) {
        const int k = i >> 7;      // 0..63
        const int m = i & 127;
        embT[k][m] = feats[(size_t)m * NF + k];
    }
    __syncthreads();

    const int tp = tid & 15;
    const int tm = tid >> 4;                 // 0..15
    const int p0 = blockIdx.x * 64 + tp * 4;
    const int m0 = tm * 8;

    float acc[8][4];
#pragma unroll
    for (int i = 0; i < 8; ++i)
#pragma unroll
        for (int q = 0; q < 4; ++q) acc[i][q] = 0.f;

#pragma unroll 8
    for (int k = 0; k < EMB_; ++k) {
        const float4 w  = *reinterpret_cast<const float4*>(&Wdec[(size_t)k * HW + p0]);
        const float4 e0 = *reinterpret_cast<const float4*>(&embT[k][m0]);
        const float4 e1 = *reinterpret_cast<const float4*>(&embT[k][m0 + 4]);
        const float ev[8] = {e0.x, e0.y, e0.z, e0.w, e1.x, e1.y, e1.z, e1.w};
#pragma unroll
        for (int i = 0; i < 8; ++i) {
            acc[i][0] = fmaf(ev[i], w.x, acc[i][0]);
            acc[i][1] = fmaf(ev[i], w.y, acc[i][1]);
            acc[i][2] = fmaf(ev[i], w.z, acc[i][2]);
            acc[i][3] = fmaf(ev[i], w.w, acc[i][3]);
        }
    }
    const float4 bd = *reinterpret_cast<const float4*>(&bdec[p0]);
#pragma unroll
    for (int i = 0; i < 8; ++i) {
        float4 o;
        o.x = acc[i][0] + bd.x;
        o.y = acc[i][1] + bd.y;
        o.z = acc[i][2] + bd.z;
        o.w = acc[i][3] + bd.w;
        *reinterpret_cast<float4*>(&pred[(size_t)(m0 + i) * HW + p0]) = o;
    }
}

// ---------------- Bilinear affine grid-sample (zero padding) ----------------
__global__ __launch_bounds__(256) void gsample_k(
    const float* __restrict__ src, float* __restrict__ dst,
    const float* __restrict__ feats, int theta_sel)
{
    const int b  = blockIdx.x >> 8;
    const int y  = blockIdx.x & 255;
    const int xq = threadIdx.x;

    const float* th = feats + (size_t)b * NF + EMB_ + theta_sel * 6;
    const float t00 = th[0], t01 = th[1], t02 = th[2];
    const float t10 = th[3], t11 = th[4], t12 = th[5];

    const float X = (float)(2 * xq + 1) * (1.f / 256.f) - 1.f;
    const float Y = (float)(2 * y  + 1) * (1.f / 256.f) - 1.f;

    const float gx = t00 * X + t01 * Y + t02;
    const float gy = t10 * X + t11 * Y + t12;

    const float ix = (gx + 1.f) * 128.f - 0.5f;
    const float iy = (gy + 1.f) * 128.f - 0.5f;
    const float ix0 = floorf(ix);
    const float iy0 = floorf(iy);
    const float wx1 = ix - ix0, wx0 = 1.f - wx1;
    const float wy1 = iy - iy0, wy0 = 1.f - wy1;

    const float* sb = src + ((size_t)b << 16);
    auto tap = [&](float xf, float yf) -> float {
        const bool valid = (xf >= 0.f) && (xf < 256.f) &&
                           (yf >= 0.f) && (yf < 256.f);
        const int xi = (int)fminf(fmaxf(xf, 0.f), 255.f);
        const int yi = (int)fminf(fmaxf(yf, 0.f), 255.f);
        const float v = sb[(yi << 8) + xi];
        return valid ? v : 0.f;
    };
    const float v00 = tap(ix0,       iy0);
    const float v10 = tap(ix0 + 1.f, iy0);
    const float v01 = tap(ix0,       iy0 + 1.f);
    const float v11 = tap(ix0 + 1.f, iy0 + 1.f);

    dst[((size_t)blockIdx.x << 8) + xq] =
        v00 * (wx0 * wy0) + v10 * (wx1 * wy0) +
        v01 * (wx0 * wy1) + v11 * (wx1 * wy1);
}

extern "C" void kernel_launch(void* const* d_in, const int* in_sizes, int n_in,
                              void* d_out, int out_size, void* d_ws, size_t ws_size,
                              hipStream_t stream)
{
    const float* x    = (const float*)d_in[0];
    const float* Wenc = (const float*)d_in[1];
    const float* benc = (const float*)d_in[2];
    const float* Wdec = (const float*)d_in[3];
    const float* bdec = (const float*)d_in[4];
    float* out = (float*)d_out;

    float* ws       = (float*)d_ws;
    float* partial  = ws;                     // 512*10496 floats = 21.5 MB
    float* imgA     = ws;                     // 33.5 MB (reused after reduce consumed partial)
    float* feats    = ws + (size_t)B_ * HW;   // 10496 floats
    float* partial2 = out;                    // 16*10496 floats, lives in d_out (overwritten later)

    enc_partial_k<<<KCH, 512, 0, stream>>>(x, Wenc, partial);
    enc_reduce1<<<dim3((BNF + 255) / 256, CB2), 256, 0, stream>>>(partial, partial2);
    enc_reduce2<<<(BNF + 255) / 256, 256, 0, stream>>>(partial2, benc, feats);
    decoder_k<<<HW / 64, 256, 0, stream>>>(feats, Wdec, bdec, imgA);
    // reference order: grid_3 (translation), grid_1 (scaler_shear), grid_2 (rotation)
    gsample_k<<<B_ * H_, 256, 0, stream>>>(imgA, out, feats, 2);
    gsample_k<<<B_ * H_, 256, 0, stream>>>(out, imgA, feats, 0);
    gsample_k<<<B_ * H_, 256, 0, stream>>>(imgA, out, feats, 1);
}

// Round 3
// 149.981 us; speedup vs baseline: 1.2891x; 1.0457x over previous
//
#include <hip/hip_runtime.h>
#include <cstddef>

namespace {
constexpr int B_   = 128;
constexpr int H_   = 256;
constexpr int W2_  = 256;
constexpr int HW   = H_ * W2_;     // 65536
constexpr int EMB_ = 64;
constexpr int NF   = EMB_ + 18;    // 82
constexpr int BNF  = B_ * NF;      // 10496
constexpr int KCH  = 512;          // k-chunks (grid of stage 1)
constexpr int KC   = HW / KCH;     // 128 k per block
constexpr int KB   = 64;           // k per LDS stage (2 stages per block)
constexpr int CB2  = 16;           // c-blocks in reduce level 1
}

// ---------------- Encoder stage 1: split-K, LDS-tiled both operands ----------
// Block (512 thr) computes full 128m x 82n partial for its 128-k chunk.
// Thread tile: 4m x 6n. xs is [k][m] (transposed) for contiguous-m b128 reads.
__global__ __launch_bounds__(512) void enc_partial_k(
    const float* __restrict__ x, const float* __restrict__ Wenc,
    float* __restrict__ partial)
{
    __shared__ __align__(16) float xs[KB][132];        // [k][m], pad 4
    __shared__ __align__(16) float wsf[KB * NF + 16];  // flat [k*82+n]

    const int tid = threadIdx.x;
    const int k0  = blockIdx.x * KC;
    const int tm  = tid >> 4;       // 0..31
    const int tn  = tid & 15;       // 0..15
    const int m0  = tm * 4;
    const int n0  = tn * 6;         // 0,6,...,90 (n0>=82 lanes compute garbage, never store)

    float acc[4][6];
#pragma unroll
    for (int i = 0; i < 4; ++i)
#pragma unroll
        for (int j = 0; j < 6; ++j) acc[i][j] = 0.f;

    for (int ks = 0; ks < KC; ks += KB) {
        __syncthreads();
        // stage x[*, k0+ks .. +63] transposed into xs[k][m]
        {
            const int m  = tid >> 2;       // 0..127
            const int fp = tid & 3;
#pragma unroll
            for (int s = 0; s < 4; ++s) {
                const int f = fp + 4 * s;  // 0..15
                const float4 v = *reinterpret_cast<const float4*>(
                    &x[(size_t)m * HW + (size_t)(k0 + ks) + f * 4]);
                xs[f * 4 + 0][m] = v.x;
                xs[f * 4 + 1][m] = v.y;
                xs[f * 4 + 2][m] = v.z;
                xs[f * 4 + 3][m] = v.w;
            }
        }
        // stage Wenc rows k0+ks .. +63 (flat contiguous: KB*82 = 5248 floats)
        {
            const float4* src = reinterpret_cast<const float4*>(
                Wenc + (size_t)(k0 + ks) * NF);
            float4* dst = reinterpret_cast<float4*>(wsf);
            for (int i4 = tid; i4 < (KB * NF) / 4; i4 += 512)
                dst[i4] = src[i4];
        }
        __syncthreads();

#pragma unroll 4
        for (int kk = 0; kk < KB; ++kk) {
            const float4 ev = *reinterpret_cast<const float4*>(&xs[kk][m0]);
            const float* wr = &wsf[kk * NF + n0];
            float w[6];
#pragma unroll
            for (int j = 0; j < 6; ++j) w[j] = wr[j];
#pragma unroll
            for (int j = 0; j < 6; ++j) {
                acc[0][j] = fmaf(ev.x, w[j], acc[0][j]);
                acc[1][j] = fmaf(ev.y, w[j], acc[1][j]);
                acc[2][j] = fmaf(ev.z, w[j], acc[2][j]);
                acc[3][j] = fmaf(ev.w, w[j], acc[3][j]);
            }
        }
    }

    if (n0 < NF) {
        float* pout = partial + (size_t)blockIdx.x * BNF;
#pragma unroll
        for (int i = 0; i < 4; ++i)
#pragma unroll
            for (int j = 0; j < 6; ++j)
                if (n0 + j < NF) pout[(m0 + i) * NF + n0 + j] = acc[i][j];
    }
}

// ---------------- Encoder reduce, level 1: 512 -> 16 ----------------
__global__ __launch_bounds__(256) void enc_reduce1(
    const float* __restrict__ partial, float* __restrict__ partial2)
{
    const int i = blockIdx.x * 256 + threadIdx.x;
    if (i >= BNF) return;
    const float* p = partial + (size_t)blockIdx.y * (KCH / CB2) * BNF + i;
    float s = 0.f;
#pragma unroll 8
    for (int c = 0; c < KCH / CB2; ++c) s += p[(size_t)c * BNF];
    partial2[(size_t)blockIdx.y * BNF + i] = s;
}

// ---------------- Encoder reduce, level 2: 16 -> 1 (+bias) ----------------
__global__ __launch_bounds__(256) void enc_reduce2(
    const float* __restrict__ partial2, const float* __restrict__ benc,
    float* __restrict__ feats)
{
    const int i = blockIdx.x * 256 + threadIdx.x;
    if (i >= BNF) return;
    float s = benc[i % NF];
#pragma unroll
    for (int j = 0; j < CB2; ++j) s += partial2[(size_t)j * BNF + i];
    feats[i] = s;
}

// ---------------- Decoder GEMM: pred = emb @ W_dec + b_dec ----------------
// 2048 blocks: blockIdx = mh*1024 + pb. Each block: 64 m-rows x 64-col tile.
// Thread tile 4m x 4p. embT padded [64][65]: stage writes 2-way (free),
// inner reads 4-address broadcast, conflict-free.
__global__ __launch_bounds__(256) void decoder_k(
    const float* __restrict__ feats, const float* __restrict__ Wdec,
    const float* __restrict__ bdec, float* __restrict__ pred)
{
    __shared__ float embT[EMB_][65];   // 16.6 KB
    const int tid   = threadIdx.x;
    const int pb    = blockIdx.x & 1023;
    const int mbase = (blockIdx.x >> 10) << 6;   // 0 or 64

    {
        const int k  = tid & 63;       // coalesced 256B per row read
        const int ms = tid >> 6;       // 0..3
#pragma unroll
        for (int mm = 0; mm < 64; mm += 4)
            embT[k][mm + ms] = feats[(size_t)(mbase + mm + ms) * NF + k];
    }
    __syncthreads();

    const int tp = tid & 15;
    const int tm = tid >> 4;                 // 0..15
    const int p0 = pb * 64 + tp * 4;
    const int m0 = tm * 4;

    float acc[4][4];
#pragma unroll
    for (int i = 0; i < 4; ++i)
#pragma unroll
        for (int q = 0; q < 4; ++q) acc[i][q] = 0.f;

#pragma unroll 4
    for (int k = 0; k < EMB_; ++k) {
        const float4 w = *reinterpret_cast<const float4*>(&Wdec[(size_t)k * HW + p0]);
        float e[4];
#pragma unroll
        for (int i = 0; i < 4; ++i) e[i] = embT[k][m0 + i];
#pragma unroll
        for (int i = 0; i < 4; ++i) {
            acc[i][0] = fmaf(e[i], w.x, acc[i][0]);
            acc[i][1] = fmaf(e[i], w.y, acc[i][1]);
            acc[i][2] = fmaf(e[i], w.z, acc[i][2]);
            acc[i][3] = fmaf(e[i], w.w, acc[i][3]);
        }
    }
    const float4 bd = *reinterpret_cast<const float4*>(&bdec[p0]);
#pragma unroll
    for (int i = 0; i < 4; ++i) {
        float4 o;
        o.x = acc[i][0] + bd.x;
        o.y = acc[i][1] + bd.y;
        o.z = acc[i][2] + bd.z;
        o.w = acc[i][3] + bd.w;
        *reinterpret_cast<float4*>(&pred[(size_t)(mbase + m0 + i) * HW + p0]) = o;
    }
}

// ---------------- Bilinear affine grid-sample (zero padding) ----------------
__global__ __launch_bounds__(256) void gsample_k(
    const float* __restrict__ src, float* __restrict__ dst,
    const float* __restrict__ feats, int theta_sel)
{
    const int b  = blockIdx.x >> 8;
    const int y  = blockIdx.x & 255;
    const int xq = threadIdx.x;

    const float* th = feats + (size_t)b * NF + EMB_ + theta_sel * 6;
    const float t00 = th[0], t01 = th[1], t02 = th[2];
    const float t10 = th[3], t11 = th[4], t12 = th[5];

    const float X = (float)(2 * xq + 1) * (1.f / 256.f) - 1.f;
    const float Y = (float)(2 * y  + 1) * (1.f / 256.f) - 1.f;

    const float gx = t00 * X + t01 * Y + t02;
    const float gy = t10 * X + t11 * Y + t12;

    const float ix = (gx + 1.f) * 128.f - 0.5f;
    const float iy = (gy + 1.f) * 128.f - 0.5f;
    const float ix0 = floorf(ix);
    const float iy0 = floorf(iy);
    const float wx1 = ix - ix0, wx0 = 1.f - wx1;
    const float wy1 = iy - iy0, wy0 = 1.f - wy1;

    const float* sb = src + ((size_t)b << 16);
    auto tap = [&](float xf, float yf) -> float {
        const bool valid = (xf >= 0.f) && (xf < 256.f) &&
                           (yf >= 0.f) && (yf < 256.f);
        const int xi = (int)fminf(fmaxf(xf, 0.f), 255.f);
        const int yi = (int)fminf(fmaxf(yf, 0.f), 255.f);
        const float v = sb[(yi << 8) + xi];
        return valid ? v : 0.f;
    };
    const float v00 = tap(ix0,       iy0);
    const float v10 = tap(ix0 + 1.f, iy0);
    const float v01 = tap(ix0,       iy0 + 1.f);
    const float v11 = tap(ix0 + 1.f, iy0 + 1.f);

    dst[((size_t)blockIdx.x << 8) + xq] =
        v00 * (wx0 * wy0) + v10 * (wx1 * wy0) +
        v01 * (wx0 * wy1) + v11 * (wx1 * wy1);
}

extern "C" void kernel_launch(void* const* d_in, const int* in_sizes, int n_in,
                              void* d_out, int out_size, void* d_ws, size_t ws_size,
                              hipStream_t stream)
{
    const float* x    = (const float*)d_in[0];
    const float* Wenc = (const float*)d_in[1];
    const float* benc = (const float*)d_in[2];
    const float* Wdec = (const float*)d_in[3];
    const float* bdec = (const float*)d_in[4];
    float* out = (float*)d_out;

    float* ws       = (float*)d_ws;
    float* partial  = ws;                     // 512*10496 floats = 21.5 MB
    float* imgA     = ws;                     // 33.5 MB (reused after reduce consumed partial)
    float* feats    = ws + (size_t)B_ * HW;   // 10496 floats
    float* partial2 = out;                    // 16*10496 floats in d_out (overwritten later)

    enc_partial_k<<<KCH, 512, 0, stream>>>(x, Wenc, partial);
    enc_reduce1<<<dim3((BNF + 255) / 256, CB2), 256, 0, stream>>>(partial, partial2);
    enc_reduce2<<<(BNF + 255) / 256, 256, 0, stream>>>(partial2, benc, feats);
    decoder_k<<<2048, 256, 0, stream>>>(feats, Wdec, bdec, imgA);
    // reference order: grid_3 (translation), grid_1 (scaler_shear), grid_2 (rotation)
    gsample_k<<<B_ * H_, 256, 0, stream>>>(imgA, out, feats, 2);
    gsample_k<<<B_ * H_, 256, 0, stream>>>(out, imgA, feats, 0);
    gsample_k<<<B_ * H_, 256, 0, stream>>>(imgA, out, feats, 1);
}